// Round 13
// baseline (105.519 us; speedup 1.0000x reference)
//
#include <hip/hip_runtime.h>
#include <hip/hip_bf16.h>

// GPT-2 attention block: B=2, S=2048, D=768, H=12, hd=64
#define BATCH 2
#define SEQ   2048
#define DMODEL 768
#define NHEAD 12
#define HDIM  64
#define QKVD  2304   // 3*DMODEL

typedef __bf16 bf16x8 __attribute__((ext_vector_type(8)));
typedef float f32x4 __attribute__((ext_vector_type(4)));
typedef float f32x16 __attribute__((ext_vector_type(16)));

static __device__ inline f32x4 mfma16(bf16x8 a, bf16x8 b, f32x4 c) {
    return __builtin_amdgcn_mfma_f32_16x16x32_bf16(a, b, c, 0, 0, 0);
}
static __device__ inline f32x16 mfma32(bf16x8 a, bf16x8 b, f32x16 c) {
    return __builtin_amdgcn_mfma_f32_32x32x16_bf16(a, b, c, 0, 0, 0);
}

static __device__ inline unsigned short f2bf_bits(float f) {
    __hip_bfloat16 h = __float2bfloat16(f);
    return __builtin_bit_cast(unsigned short, h);
}
static __device__ inline unsigned int pack_bf16(float a, float b) {
    return (unsigned int)f2bf_bits(a) | ((unsigned int)f2bf_bits(b) << 16);
}

// async global->LDS, 16B per lane
static __device__ inline void gload16(const __hip_bfloat16* g, __hip_bfloat16* l) {
    __builtin_amdgcn_global_load_lds(
        (const __attribute__((address_space(1))) void*)g,
        (__attribute__((address_space(3))) void*)l, 16, 0, 0);
}

// ---------------- conversion kernels ----------------

__global__ __launch_bounds__(256) void f32_to_bf16_k(const float* __restrict__ in,
                                                     __hip_bfloat16* __restrict__ out) {
    int i = blockIdx.x * 256 + threadIdx.x;
    float4 v = reinterpret_cast<const float4*>(in)[i];
    ushort4 o;
    o.x = f2bf_bits(v.x); o.y = f2bf_bits(v.y);
    o.z = f2bf_bits(v.z); o.w = f2bf_bits(v.w);
    reinterpret_cast<ushort4*>(out)[i] = o;
}

__global__ __launch_bounds__(256) void transpose_f32_to_bf16(const float* __restrict__ in,
                                                             __hip_bfloat16* __restrict__ out,
                                                             int R, int C) {
    __shared__ float t[32][33];
    int tx = threadIdx.x & 31, ty = threadIdx.x >> 5;
    int bx = blockIdx.x * 32;
    int by = blockIdx.y * 32;
#pragma unroll
    for (int k = 0; k < 4; k++)
        t[ty + k * 8][tx] = in[(size_t)(by + ty + k * 8) * C + bx + tx];
    __syncthreads();
#pragma unroll
    for (int k = 0; k < 4; k++)
        out[(size_t)(bx + ty + k * 8) * R + by + tx] = __float2bfloat16(t[tx][ty + k * 8]);
}

// ---------------- pack K,V into MFMA fragment order (unchanged) ----------------

__global__ __launch_bounds__(256) void pack_kv(const __hip_bfloat16* __restrict__ qkv,
                                               __hip_bfloat16* __restrict__ Kp,
                                               __hip_bfloat16* __restrict__ Vp) {
    __shared__ __hip_bfloat16 Kl[32][72];
    __shared__ __hip_bfloat16 Vl[32][72];
    int tid = threadIdx.x;
    int q32 = blockIdx.x;            // 0..63
    int bh = blockIdx.y;             // 0..23
    int b = bh / NHEAD, h = bh - (bh / NHEAD) * NHEAD;
    int row = tid >> 3, cc = (tid & 7) * 8;
    const __hip_bfloat16* src = qkv + (size_t)(b * SEQ + q32 * 32 + row) * QKVD + h * HDIM + cc;
    *reinterpret_cast<uint4*>(&Kl[row][cc]) = *reinterpret_cast<const uint4*>(src + DMODEL);
    *reinterpret_cast<uint4*>(&Vl[row][cc]) = *reinterpret_cast<const uint4*>(src + 2 * DMODEL);
    __syncthreads();

    int l31 = tid & 31, half = (tid >> 5) & 1;
    size_t obase = (size_t)bh * 131072 + (size_t)q32 * 2048 + (size_t)tid * 8;

    int kd = tid >> 6;
    bf16x8 kf = *reinterpret_cast<const bf16x8*>(&Kl[l31][kd * 16 + half * 8]);
    *reinterpret_cast<bf16x8*>(Kp + obase) = kf;

    int ks = tid >> 7, dh = (tid >> 6) & 1;
    union { unsigned short s[8]; bf16x8 v; } vf;
#pragma unroll
    for (int i = 0; i < 8; i++)
        vf.s[i] = __builtin_bit_cast(unsigned short, Vl[ks * 16 + half * 8 + i][dh * 32 + l31]);
    *reinterpret_cast<bf16x8*>(Vp + obase) = vf.v;
}

// ---------------- GEMM: single-barrier double-buffered staging, strided-A (unchanged) ----------------

template <bool OUT_BF16>
__global__ __launch_bounds__(256) void gemm_bt(const __hip_bfloat16* __restrict__ A,
                                               const __hip_bfloat16* __restrict__ Bt,
                                               const float* __restrict__ bias,
                                               void* __restrict__ Cp,
                                               int M, int N, int K, int lda) {
    __shared__ __hip_bfloat16 Al[2][128 * 32];
    __shared__ __hip_bfloat16 Bl[2][128 * 32];

    int tid = threadIdx.x;
    int wid = tid >> 6;
    int lane = tid & 63;
    int lr = lane & 15;
    int lg = lane >> 4;
    int m0 = blockIdx.y * 128;
    int n0 = blockIdx.x * 128;
    int wm = (wid >> 1) * 64;
    int wn = (wid & 1) * 64;

    int srow = wid * 16 + (lane >> 2);
    int scol = (lane & 3) * 8;
    const __hip_bfloat16* ag = A + (size_t)(m0 + srow) * lda + scol;
    const __hip_bfloat16* bg = Bt + (size_t)(n0 + srow) * K + scol;
    int lofs = wid * 512;

    f32x4 acc[4][4] = {};

    gload16(ag, &Al[0][lofs]);
    gload16(ag + (size_t)64 * lda, &Al[0][lofs + 2048]);
    gload16(bg, &Bl[0][lofs]);
    gload16(bg + (size_t)64 * K, &Bl[0][lofs + 2048]);
    __syncthreads();

    int nk = K >> 5;
    for (int t = 0; t < nk; t++) {
        int cb = t & 1;
        if (t + 1 < nk) {
            int k0 = (t + 1) << 5;
            int nb = cb ^ 1;
            gload16(ag + k0, &Al[nb][lofs]);
            gload16(ag + (size_t)64 * lda + k0, &Al[nb][lofs + 2048]);
            gload16(bg + k0, &Bl[nb][lofs]);
            gload16(bg + (size_t)64 * K + k0, &Bl[nb][lofs + 2048]);
        }

        bf16x8 af[4], bfr[4];
#pragma unroll
        for (int i = 0; i < 4; i++)
            af[i] = *reinterpret_cast<const bf16x8*>(&Al[cb][(wm + i * 16 + lr) * 32 + lg * 8]);
#pragma unroll
        for (int j = 0; j < 4; j++)
            bfr[j] = *reinterpret_cast<const bf16x8*>(&Bl[cb][(wn + j * 16 + lr) * 32 + lg * 8]);
#pragma unroll
        for (int i = 0; i < 4; i++)
#pragma unroll
            for (int j = 0; j < 4; j++)
                acc[i][j] = mfma16(af[i], bfr[j], acc[i][j]);
        __syncthreads();
    }

#pragma unroll
    for (int i = 0; i < 4; i++) {
#pragma unroll
        for (int j = 0; j < 4; j++) {
            int col = n0 + wn + j * 16 + lr;
            float bv = bias[col];
#pragma unroll
            for (int r = 0; r < 4; r++) {
                int row = m0 + wm + i * 16 + lg * 4 + r;
                float v = acc[i][j][r] + bv;
                if (OUT_BF16)
                    ((__hip_bfloat16*)Cp)[(size_t)row * N + col] = __float2bfloat16(v);
                else
                    ((float*)Cp)[(size_t)row * N + col] = v;
            }
        }
    }
}

// ---------------- causal flash attention v13: T15 2-deep tile pipeline ----------------
// v12 (packed coalesced fragments, no LDS/barriers in loop) + software pipeline:
// QK^T(t+1) -> stB is issued BEFORE softmax/PV of stA (QK is independent of the
// online-softmax state), so the softmax VALU chain of tile t hides under the MFMA
// latency of tile t+1. Manually unrolled x2 with named stA/stB (rule #20: all
// register indices compile-time). kc fragments stay one quarter ahead.

#define KS2 0.18033688f  // 0.125 * log2(e)

__global__ __launch_bounds__(256, 4) void flash_attn(const __hip_bfloat16* __restrict__ qkv,
                                                     const __hip_bfloat16* __restrict__ Kp,
                                                     const __hip_bfloat16* __restrict__ Vp,
                                                     __hip_bfloat16* __restrict__ obase) {
    // combine-only LDS: SC_w (w=1..3) at (w-1)*8448; OL at 25344 ([32 q][72 d] bf16)
    __shared__ __align__(16) char smem[30208];

    int tid = threadIdx.x;
    int w = tid >> 6;        // wave = kv quarter parity
    int lane = tid & 63;
    int l31 = lane & 31;
    int lg2 = lane >> 5;

    // block -> (xcd-chunked head, descending q-tile)
    int wg = blockIdx.x;
    int xcd = wg & 7;
    int slot = wg >> 3;          // 0..191
    int hsl = slot % 3;
    int qsl = slot / 3;          // 0..63
    int bh = xcd * 3 + hsl;
    int it = 63 - qsl;           // largest first
    int b = bh / NHEAD;
    int h = bh - b * NHEAD;
    int q0 = it * 32;
    int bbase = b * SEQ;

    // per-wave iteration count: kv quarters 32*(4t+w) <= q0
    int Tw = (it >= w) ? ((it - w) >> 2) + 1 : 0;

    const __hip_bfloat16* Kph = Kp + (size_t)bh * 131072;
    const __hip_bfloat16* Vph = Vp + (size_t)bh * 131072;

    // Q fragments (B operand: col=q=l31, k=d)
    const __hip_bfloat16* qg = qkv + (size_t)(bbase + q0 + l31) * QKVD + h * HDIM;
    bf16x8 qf[4];
#pragma unroll
    for (int kd = 0; kd < 4; kd++)
        qf[kd] = *reinterpret_cast<const bf16x8*>(qg + kd * 16 + lg2 * 8);

    f32x16 o0 = {}, o1 = {};
    float m = -3.0e38f, l = 0.f;

    bf16x8 kc[4];
    auto loadK = [&](int qi) {
        const __hip_bfloat16* kr = Kph + (size_t)qi * 2048 + l31 * 8;
#pragma unroll
        for (int kd = 0; kd < 4; kd++)
            kc[kd] = *reinterpret_cast<const bf16x8*>(kr + (kd * 2 + lg2) * 256);
    };
    auto QK = [&]() -> f32x16 {
        __builtin_amdgcn_s_setprio(1);
        f32x16 s = {};
#pragma unroll
        for (int kd = 0; kd < 4; kd++)
            s = mfma32(kc[kd], qf[kd], s);
        __builtin_amdgcn_s_setprio(0);
        return s;
    };
    auto loadVf = [&](int qi, bf16x8* vf) {
        const __hip_bfloat16* vr = Vph + (size_t)qi * 2048 + lg2 * 256 + l31 * 8;
#pragma unroll
        for (int ks = 0; ks < 2; ks++)
#pragma unroll
            for (int dh = 0; dh < 2; dh++)
                vf[ks * 2 + dh] = *reinterpret_cast<const bf16x8*>(vr + (ks * 2 + dh) * 512);
    };
    auto process = [&](f32x16& st, int qi, const bf16x8* vf) {
        if (qi * 32 == q0) {  // diagonal subtile: causal mask
#pragma unroll
            for (int j = 0; j < 16; j++) {
                int kvl = (j & 3) + 8 * (j >> 2) + 4 * lg2;
                if (kvl > l31) st[j] = -3.0e38f;
            }
        }
        // online softmax (per-lane q=l31; halves merged via shfl 32)
        float tm[16];
#pragma unroll
        for (int j = 0; j < 16; j++) tm[j] = st[j];
#pragma unroll
        for (int dd = 8; dd >= 1; dd >>= 1)
#pragma unroll
            for (int j = 0; j < 8; j++)
                if (j < dd) tm[j] = fmaxf(tm[j], tm[j + dd]);
        float mx = fmaxf(tm[0], __shfl_xor(tm[0], 32, 64));
        bool small = __all(mx <= m + 44.0f);  // T13 defer-max
        float mnew = small ? m : fmaxf(m, mx);
#pragma unroll
        for (int j = 0; j < 16; j++)
            st[j] = __builtin_amdgcn_exp2f((st[j] - mnew) * KS2);
        float ts[16];
#pragma unroll
        for (int j = 0; j < 16; j++) ts[j] = st[j];
#pragma unroll
        for (int dd = 8; dd >= 1; dd >>= 1)
#pragma unroll
            for (int j = 0; j < 8; j++)
                if (j < dd) ts[j] += ts[j + dd];
        float ls = ts[0] + __shfl_xor(ts[0], 32, 64);
        if (small) {
            l += ls;
        } else {
            float sc = __builtin_amdgcn_exp2f((m - mnew) * KS2);
            l = l * sc + ls;
            o0 *= sc;
            o1 *= sc;
            m = mnew;
        }
        // in-register P repack (4 shfl) + PV
#pragma unroll
        for (int ks = 0; ks < 2; ks++) {
            unsigned int a0 = pack_bf16(st[8 * ks + 0], st[8 * ks + 1]);
            unsigned int a1 = pack_bf16(st[8 * ks + 2], st[8 * ks + 3]);
            unsigned int b0 = pack_bf16(st[8 * ks + 4], st[8 * ks + 5]);
            unsigned int b1 = pack_bf16(st[8 * ks + 6], st[8 * ks + 7]);
            unsigned int y0 = lg2 ? a0 : b0;
            unsigned int y1 = lg2 ? a1 : b1;
            unsigned int p0 = __shfl_xor(y0, 32, 64);
            unsigned int p1 = __shfl_xor(y1, 32, 64);
            union { unsigned int u[4]; bf16x8 v; } pf;
            pf.u[0] = lg2 ? p0 : a0;
            pf.u[1] = lg2 ? p1 : a1;
            pf.u[2] = lg2 ? b0 : p0;
            pf.u[3] = lg2 ? b1 : p1;
            __builtin_amdgcn_s_setprio(1);
            o0 = mfma32(vf[ks * 2 + 0], pf.v, o0);
            o1 = mfma32(vf[ks * 2 + 1], pf.v, o1);
            __builtin_amdgcn_s_setprio(0);
        }
    };

    // ---- 2-deep pipelined main loop ----
    f32x16 stA, stB;
    if (Tw > 0) {
        loadK(w);
        stA = QK();               // quarter w
        if (Tw > 1) loadK(w + 4);
    }
    for (int t = 0; t < Tw; t += 2) {
        int qiA = 4 * t + w;
        bf16x8 vfA[4];
        loadVf(qiA, vfA);
        if (t + 1 < Tw) {
            stB = QK();           // quarter qiA+4 (kc holds it)
            if (t + 2 < Tw) loadK(qiA + 8);
        }
        process(stA, qiA, vfA);
        if (t + 1 < Tw) {
            int qiB = qiA + 4;
            bf16x8 vfB[4];
            loadVf(qiB, vfB);
            if (t + 2 < Tw) {
                stA = QK();       // quarter qiA+8
                if (t + 3 < Tw) loadK(qiA + 12);
            }
            process(stB, qiB, vfB);
        }
    }

    __syncthreads();  // waves done before combine staging

    // ---- 4-way combine: waves 1..3 stage (o,m,l); wave 0 merges ----
    if (w != 0) {
        float* SCw = (float*)(smem + (w - 1) * 8448);
#pragma unroll
        for (int j = 0; j < 16; j++) {
            int dl = (j & 3) + 8 * (j >> 2) + 4 * lg2;
            SCw[dl * 32 + l31] = o0[j];
            SCw[(32 + dl) * 32 + l31] = o1[j];
        }
        if (lg2 == 0) {
            SCw[2048 + l31] = m;
            SCw[2048 + 32 + l31] = l;
        }
    }
    __syncthreads();
    if (w == 0) {
        float* SC1 = (float*)(smem + 0);
        float* SC2 = (float*)(smem + 8448);
        float* SC3 = (float*)(smem + 16896);
        __hip_bfloat16* OL = (__hip_bfloat16*)(smem + 25344);
        float m1 = SC1[2048 + l31], l1 = SC1[2048 + 32 + l31];
        float m2 = SC2[2048 + l31], l2 = SC2[2048 + 32 + l31];
        float m3 = SC3[2048 + l31], l3 = SC3[2048 + 32 + l31];
        float M = fmaxf(fmaxf(m, m1), fmaxf(m2, m3));
        float e0 = __builtin_amdgcn_exp2f((m - M) * KS2);
        float e1 = __builtin_amdgcn_exp2f((m1 - M) * KS2);
        float e2 = __builtin_amdgcn_exp2f((m2 - M) * KS2);
        float e3 = __builtin_amdgcn_exp2f((m3 - M) * KS2);
        float L = l * e0 + l1 * e1 + l2 * e2 + l3 * e3;
        float linv = 1.0f / L;
#pragma unroll
        for (int od = 0; od < 2; od++) {
#pragma unroll
            for (int g = 0; g < 4; g++) {
                int dbase = od * 32 + 8 * g + 4 * lg2;
                ushort4 w4;
#pragma unroll
                for (int r = 0; r < 4; r++) {
                    int d = dbase + r;
                    float self = od ? o1[4 * g + r] : o0[4 * g + r];
                    float v = self * e0 + SC1[d * 32 + l31] * e1 +
                              SC2[d * 32 + l31] * e2 + SC3[d * 32 + l31] * e3;
                    v *= linv;
                    ((unsigned short*)&w4)[r] = f2bf_bits(v);
                }
                *reinterpret_cast<ushort4*>(&OL[l31 * 72 + dbase]) = w4;
            }
        }
    }
    __syncthreads();
    // coalesced store into QKV K-column hole: O[token][h*64+c] at stride QKVD
    {
        __hip_bfloat16* OL = (__hip_bfloat16*)(smem + 25344);
        int r = tid >> 3, c = (tid & 7) * 8;
        __hip_bfloat16* dst = obase + (size_t)(bbase + q0 + r) * QKVD + h * HDIM + c;
        *reinterpret_cast<uint4*>(dst) = *reinterpret_cast<const uint4*>(&OL[r * 72 + c]);
    }
}

// ---------------- launch ----------------

extern "C" void kernel_launch(void* const* d_in, const int* in_sizes, int n_in,
                              void* d_out, int out_size, void* d_ws, size_t ws_size,
                              hipStream_t stream) {
    const float* hidden = (const float*)d_in[0];   // [2,2048,768]
    const float* w_attn = (const float*)d_in[1];   // [768,2304]
    const float* b_attn = (const float*)d_in[2];   // [2304]
    const float* w_proj = (const float*)d_in[3];   // [768,768]
    const float* b_proj = (const float*)d_in[4];   // [768]
    float* out = (float*)d_out;                    // [2,2048,768]

    char* ws = (char*)d_ws;
    __hip_bfloat16* Xb  = (__hip_bfloat16*)(ws + 0);         // 4096*768*2 = 6291456
    __hip_bfloat16* Wta = (__hip_bfloat16*)(ws + 6291456);   // 2304*768*2
    __hip_bfloat16* Wtp = (__hip_bfloat16*)(ws + 9830400);   // 768*768*2
    __hip_bfloat16* QKV = (__hip_bfloat16*)(ws + 11010048);  // 4096*2304*2
    // packed fragments (after their sources are dead):
    __hip_bfloat16* Kpb = (__hip_bfloat16*)(ws + 0);         // aliases Xb: 24*131072*2 = 6291456
    __hip_bfloat16* Vpb = (__hip_bfloat16*)(ws + 29884416);  // old AO region: 6291456

    const int M = BATCH * SEQ;  // 4096

    f32_to_bf16_k<<<dim3(M * DMODEL / (256 * 4)), dim3(256), 0, stream>>>(hidden, Xb);
    transpose_f32_to_bf16<<<dim3(QKVD / 32, DMODEL / 32), dim3(256), 0, stream>>>(w_attn, Wta, DMODEL, QKVD);
    transpose_f32_to_bf16<<<dim3(DMODEL / 32, DMODEL / 32), dim3(256), 0, stream>>>(w_proj, Wtp, DMODEL, DMODEL);
    gemm_bt<true><<<dim3(QKVD / 128, M / 128), dim3(256), 0, stream>>>(Xb, Wta, b_attn, QKV, M, QKVD, DMODEL, DMODEL);
    pack_kv<<<dim3(SEQ / 32, BATCH * NHEAD), dim3(256), 0, stream>>>(QKV, Kpb, Vpb);
    // flash writes O into QKV's (dead) K columns: obase = QKV + DMODEL, row stride QKVD
    flash_attn<<<dim3(1536), dim3(256), 0, stream>>>(QKV, Kpb, Vpb, QKV + DMODEL);
    gemm_bt<false><<<dim3(DMODEL / 128, M / 128), dim3(256), 0, stream>>>(QKV + DMODEL, Wtp, b_proj, out, M, DMODEL, DMODEL, QKVD);
}

// Round 14
// 88.334 us; speedup vs baseline: 1.1945x; 1.1945x over previous
//
#include <hip/hip_runtime.h>
#include <hip/hip_bf16.h>

// GPT-2 attention block: B=2, S=2048, D=768, H=12, hd=64
#define BATCH 2
#define SEQ   2048
#define DMODEL 768
#define NHEAD 12
#define HDIM  64
#define QKVD  2304   // 3*DMODEL

typedef __bf16 bf16x8 __attribute__((ext_vector_type(8)));
typedef float f32x4 __attribute__((ext_vector_type(4)));
typedef float f32x16 __attribute__((ext_vector_type(16)));

static __device__ inline f32x4 mfma16(bf16x8 a, bf16x8 b, f32x4 c) {
    return __builtin_amdgcn_mfma_f32_16x16x32_bf16(a, b, c, 0, 0, 0);
}
static __device__ inline f32x16 mfma32(bf16x8 a, bf16x8 b, f32x16 c) {
    return __builtin_amdgcn_mfma_f32_32x32x16_bf16(a, b, c, 0, 0, 0);
}

static __device__ inline unsigned short f2bf_bits(float f) {
    __hip_bfloat16 h = __float2bfloat16(f);
    return __builtin_bit_cast(unsigned short, h);
}
static __device__ inline unsigned int pack_bf16(float a, float b) {
    return (unsigned int)f2bf_bits(a) | ((unsigned int)f2bf_bits(b) << 16);
}

// async global->LDS, 16B per lane
static __device__ inline void gload16(const __hip_bfloat16* g, __hip_bfloat16* l) {
    __builtin_amdgcn_global_load_lds(
        (const __attribute__((address_space(1))) void*)g,
        (__attribute__((address_space(3))) void*)l, 16, 0, 0);
}

// ---------------- conversion kernels ----------------

__global__ __launch_bounds__(256) void f32_to_bf16_k(const float* __restrict__ in,
                                                     __hip_bfloat16* __restrict__ out) {
    int i = blockIdx.x * 256 + threadIdx.x;
    float4 v = reinterpret_cast<const float4*>(in)[i];
    ushort4 o;
    o.x = f2bf_bits(v.x); o.y = f2bf_bits(v.y);
    o.z = f2bf_bits(v.z); o.w = f2bf_bits(v.w);
    reinterpret_cast<ushort4*>(out)[i] = o;
}

__global__ __launch_bounds__(256) void transpose_f32_to_bf16(const float* __restrict__ in,
                                                             __hip_bfloat16* __restrict__ out,
                                                             int R, int C) {
    __shared__ float t[32][33];
    int tx = threadIdx.x & 31, ty = threadIdx.x >> 5;
    int bx = blockIdx.x * 32;
    int by = blockIdx.y * 32;
#pragma unroll
    for (int k = 0; k < 4; k++)
        t[ty + k * 8][tx] = in[(size_t)(by + ty + k * 8) * C + bx + tx];
    __syncthreads();
#pragma unroll
    for (int k = 0; k < 4; k++)
        out[(size_t)(bx + ty + k * 8) * R + by + tx] = __float2bfloat16(t[tx][ty + k * 8]);
}

// ---------------- QKV GEMM with packed-fragment epilogue ----------------
// Same 128x128/BK=32 dbuf loop as gemm_bt; epilogue writes each C element directly to
// Qp/Kp/Vp in MFMA fragment order (layouts identical to the verified pack_kv):
//   Q/K (token,d): off = bh*131072 + (tok>>5)*2048 + ((d/16*2 + (d%16)/8)*32 + tok%32)*8 + d%8
//   V   (token,d): off = bh*131072 + (tok>>5)*2048 + ((((tok%32)/16*2 + d/32)*2 + (tok%16)/8)*32 + d%32)*8 + tok%8
// V's 4 consecutive tokens are contiguous -> ushort4 stores.

__global__ __launch_bounds__(256) void gemm_qkv(const __hip_bfloat16* __restrict__ A,
                                                const __hip_bfloat16* __restrict__ Bt,
                                                const float* __restrict__ bias,
                                                __hip_bfloat16* __restrict__ Qp,
                                                __hip_bfloat16* __restrict__ Kp,
                                                __hip_bfloat16* __restrict__ Vp,
                                                int M, int N, int K) {
    __shared__ __hip_bfloat16 Al[2][128 * 32];
    __shared__ __hip_bfloat16 Bl[2][128 * 32];

    int tid = threadIdx.x;
    int wid = tid >> 6;
    int lane = tid & 63;
    int lr = lane & 15;
    int lg = lane >> 4;
    int m0 = blockIdx.y * 128;
    int n0 = blockIdx.x * 128;
    int wm = (wid >> 1) * 64;
    int wn = (wid & 1) * 64;

    int srow = wid * 16 + (lane >> 2);
    int scol = (lane & 3) * 8;
    const __hip_bfloat16* ag = A + (size_t)(m0 + srow) * K + scol;
    const __hip_bfloat16* bg = Bt + (size_t)(n0 + srow) * K + scol;
    int lofs = wid * 512;

    f32x4 acc[4][4] = {};

    gload16(ag, &Al[0][lofs]);
    gload16(ag + (size_t)64 * K, &Al[0][lofs + 2048]);
    gload16(bg, &Bl[0][lofs]);
    gload16(bg + (size_t)64 * K, &Bl[0][lofs + 2048]);
    __syncthreads();

    int nk = K >> 5;
    for (int t = 0; t < nk; t++) {
        int cb = t & 1;
        if (t + 1 < nk) {
            int k0 = (t + 1) << 5;
            int nb = cb ^ 1;
            gload16(ag + k0, &Al[nb][lofs]);
            gload16(ag + (size_t)64 * K + k0, &Al[nb][lofs + 2048]);
            gload16(bg + k0, &Bl[nb][lofs]);
            gload16(bg + (size_t)64 * K + k0, &Bl[nb][lofs + 2048]);
        }

        bf16x8 af[4], bfr[4];
#pragma unroll
        for (int i = 0; i < 4; i++)
            af[i] = *reinterpret_cast<const bf16x8*>(&Al[cb][(wm + i * 16 + lr) * 32 + lg * 8]);
#pragma unroll
        for (int j = 0; j < 4; j++)
            bfr[j] = *reinterpret_cast<const bf16x8*>(&Bl[cb][(wn + j * 16 + lr) * 32 + lg * 8]);
#pragma unroll
        for (int i = 0; i < 4; i++)
#pragma unroll
            for (int j = 0; j < 4; j++)
                acc[i][j] = mfma16(af[i], bfr[j], acc[i][j]);
        __syncthreads();
    }

#pragma unroll
    for (int j = 0; j < 4; j++) {
        int col = n0 + wn + j * 16 + lr;
        float bv = bias[col];
        int reg = col / DMODEL;                 // 0=Q,1=K,2=V (uniform per j)
        int cm = col - reg * DMODEL;
        int h = cm >> 6;                        // uniform per j
        int dd = cm & 63;
        __hip_bfloat16* dstQK = (reg == 0) ? Qp : Kp;
        if (reg < 2) {
            int kd = dd >> 4, half = (dd >> 3) & 1, e = dd & 7;
            int tbase = (kd * 2 + half) * 32;
#pragma unroll
            for (int i = 0; i < 4; i++) {
#pragma unroll
                for (int r = 0; r < 4; r++) {
                    int row = m0 + wm + i * 16 + lg * 4 + r;
                    int bq = row >> 11, tok = row & 2047;
                    size_t off = (size_t)(bq * NHEAD + h) * 131072 + (size_t)(tok >> 5) * 2048
                               + (size_t)(tbase + (tok & 31)) * 8 + e;
                    dstQK[off] = __float2bfloat16(acc[i][j][r] + bv);
                }
            }
        } else {
            int dh = dd >> 5, l31v = dd & 31;
#pragma unroll
            for (int i = 0; i < 4; i++) {
                int row0 = m0 + wm + i * 16 + lg * 4;
                int bq = row0 >> 11, tok0 = row0 & 2047;
                int ks = (tok0 >> 4) & 1, half = (tok0 >> 3) & 1;
                size_t off = (size_t)(bq * NHEAD + h) * 131072 + (size_t)(tok0 >> 5) * 2048
                           + (size_t)((((ks * 2 + dh) * 2 + half) * 32) + l31v) * 8 + (tok0 & 7);
                ushort4 w4;
                w4.x = f2bf_bits(acc[i][j][0] + bv);
                w4.y = f2bf_bits(acc[i][j][1] + bv);
                w4.z = f2bf_bits(acc[i][j][2] + bv);
                w4.w = f2bf_bits(acc[i][j][3] + bv);
                *reinterpret_cast<ushort4*>(Vp + off) = w4;
            }
        }
    }
}

// ---------------- GEMM: single-barrier double-buffered staging, strided-A (unchanged) ----------------

template <bool OUT_BF16>
__global__ __launch_bounds__(256) void gemm_bt(const __hip_bfloat16* __restrict__ A,
                                               const __hip_bfloat16* __restrict__ Bt,
                                               const float* __restrict__ bias,
                                               void* __restrict__ Cp,
                                               int M, int N, int K, int lda) {
    __shared__ __hip_bfloat16 Al[2][128 * 32];
    __shared__ __hip_bfloat16 Bl[2][128 * 32];

    int tid = threadIdx.x;
    int wid = tid >> 6;
    int lane = tid & 63;
    int lr = lane & 15;
    int lg = lane >> 4;
    int m0 = blockIdx.y * 128;
    int n0 = blockIdx.x * 128;
    int wm = (wid >> 1) * 64;
    int wn = (wid & 1) * 64;

    int srow = wid * 16 + (lane >> 2);
    int scol = (lane & 3) * 8;
    const __hip_bfloat16* ag = A + (size_t)(m0 + srow) * lda + scol;
    const __hip_bfloat16* bg = Bt + (size_t)(n0 + srow) * K + scol;
    int lofs = wid * 512;

    f32x4 acc[4][4] = {};

    gload16(ag, &Al[0][lofs]);
    gload16(ag + (size_t)64 * lda, &Al[0][lofs + 2048]);
    gload16(bg, &Bl[0][lofs]);
    gload16(bg + (size_t)64 * K, &Bl[0][lofs + 2048]);
    __syncthreads();

    int nk = K >> 5;
    for (int t = 0; t < nk; t++) {
        int cb = t & 1;
        if (t + 1 < nk) {
            int k0 = (t + 1) << 5;
            int nb = cb ^ 1;
            gload16(ag + k0, &Al[nb][lofs]);
            gload16(ag + (size_t)64 * lda + k0, &Al[nb][lofs + 2048]);
            gload16(bg + k0, &Bl[nb][lofs]);
            gload16(bg + (size_t)64 * K + k0, &Bl[nb][lofs + 2048]);
        }

        bf16x8 af[4], bfr[4];
#pragma unroll
        for (int i = 0; i < 4; i++)
            af[i] = *reinterpret_cast<const bf16x8*>(&Al[cb][(wm + i * 16 + lr) * 32 + lg * 8]);
#pragma unroll
        for (int j = 0; j < 4; j++)
            bfr[j] = *reinterpret_cast<const bf16x8*>(&Bl[cb][(wn + j * 16 + lr) * 32 + lg * 8]);
#pragma unroll
        for (int i = 0; i < 4; i++)
#pragma unroll
            for (int j = 0; j < 4; j++)
                acc[i][j] = mfma16(af[i], bfr[j], acc[i][j]);
        __syncthreads();
    }

#pragma unroll
    for (int i = 0; i < 4; i++) {
#pragma unroll
        for (int j = 0; j < 4; j++) {
            int col = n0 + wn + j * 16 + lr;
            float bv = bias[col];
#pragma unroll
            for (int r = 0; r < 4; r++) {
                int row = m0 + wm + i * 16 + lg * 4 + r;
                float v = acc[i][j][r] + bv;
                if (OUT_BF16)
                    ((__hip_bfloat16*)Cp)[(size_t)row * N + col] = __float2bfloat16(v);
                else
                    ((float*)Cp)[(size_t)row * N + col] = v;
            }
        }
    }
}

// ---------------- causal flash attention v14 = v12 (known-good) + packed Q prologue ----------------
// grid 1536 = 24 bh x 64 q-tiles (largest first, XCD-chunked), block 256 = 4 waves.
// Wave w owns kv quarter qi=4t+w. Q, K, V fragments all read from packed Qp/Kp/Vp:
// every load is a fully-coalesced 1KB wave-load. No LDS/barriers in loop. In-register
// P repack (4 shfl), T13 defer-max, setprio. O -> plain [4096][768] buffer.

#define KS2 0.18033688f  // 0.125 * log2(e)

__global__ __launch_bounds__(256, 4) void flash_attn(const __hip_bfloat16* __restrict__ Qp,
                                                     const __hip_bfloat16* __restrict__ Kp,
                                                     const __hip_bfloat16* __restrict__ Vp,
                                                     __hip_bfloat16* __restrict__ AO) {
    // combine-only LDS: SC_w (w=1..3) at (w-1)*8448; OL at 25344 ([32 q][72 d] bf16)
    __shared__ __align__(16) char smem[30208];

    int tid = threadIdx.x;
    int w = tid >> 6;        // wave = kv quarter parity
    int lane = tid & 63;
    int l31 = lane & 31;
    int lg2 = lane >> 5;

    // block -> (xcd-chunked head, descending q-tile)
    int wg = blockIdx.x;
    int xcd = wg & 7;
    int slot = wg >> 3;          // 0..191
    int hsl = slot % 3;
    int qsl = slot / 3;          // 0..63
    int bh = xcd * 3 + hsl;
    int it = 63 - qsl;           // largest first
    int b = bh / NHEAD;
    int h = bh - b * NHEAD;
    int q0 = it * 32;
    int bbase = b * SEQ;

    // per-wave iteration count: kv quarters 32*(4t+w) <= q0
    int Tw = (it >= w) ? ((it - w) >> 2) + 1 : 0;

    const __hip_bfloat16* Kph = Kp + (size_t)bh * 131072;
    const __hip_bfloat16* Vph = Vp + (size_t)bh * 131072;

    // Q fragments: coalesced packed load (same layout as K)
    bf16x8 qf[4];
    {
        const __hip_bfloat16* qr = Qp + (size_t)bh * 131072 + (size_t)it * 2048 + l31 * 8;
#pragma unroll
        for (int kd = 0; kd < 4; kd++)
            qf[kd] = *reinterpret_cast<const bf16x8*>(qr + (kd * 2 + lg2) * 256);
    }

    f32x16 o0 = {}, o1 = {};
    float m = -3.0e38f, l = 0.f;

    bf16x8 kc[4];
    // prologue: K fragments for quarter qi=w (coalesced)
    {
        const __hip_bfloat16* kr = Kph + (size_t)w * 2048 + l31 * 8;
#pragma unroll
        for (int kd = 0; kd < 4; kd++)
            kc[kd] = *reinterpret_cast<const bf16x8*>(kr + (kd * 2 + lg2) * 256);
    }

    for (int t = 0; t < Tw; t++) {
        int qi = 4 * t + w;
        int kvbase = qi * 32;
        bool hn = (t + 1 < Tw);

        // ---- V^T fragments: coalesced packed loads, issued early ----
        const __hip_bfloat16* vr = Vph + (size_t)qi * 2048 + lg2 * 256 + l31 * 8;
        bf16x8 vf[4];
#pragma unroll
        for (int ks = 0; ks < 2; ks++)
#pragma unroll
            for (int dh = 0; dh < 2; dh++)
                vf[ks * 2 + dh] = *reinterpret_cast<const bf16x8*>(vr + (ks * 2 + dh) * 512);

        // ---- S^T = mfma32(K, Q): col=q=l31, row kv_local=(j&3)+8*(j>>2)+4*lg2 ----
        __builtin_amdgcn_s_setprio(1);
        f32x16 st = {};
#pragma unroll
        for (int kd = 0; kd < 4; kd++)
            st = mfma32(kc[kd], qf[kd], st);
        __builtin_amdgcn_s_setprio(0);

        if (hn) {  // kc consumed: reload next quarter (coalesced, L2-resident)
            const __hip_bfloat16* kr = Kph + (size_t)(qi + 4) * 2048 + l31 * 8;
#pragma unroll
            for (int kd = 0; kd < 4; kd++)
                kc[kd] = *reinterpret_cast<const bf16x8*>(kr + (kd * 2 + lg2) * 256);
        }

        if (kvbase == q0) {  // diagonal subtile: causal mask
#pragma unroll
            for (int j = 0; j < 16; j++) {
                int kvl = (j & 3) + 8 * (j >> 2) + 4 * lg2;
                if (kvl > l31) st[j] = -3.0e38f;
            }
        }
        // ---- online softmax (per-lane q=l31; halves merged via shfl 32) ----
        float tm[16];
#pragma unroll
        for (int j = 0; j < 16; j++) tm[j] = st[j];
#pragma unroll
        for (int dd = 8; dd >= 1; dd >>= 1)
#pragma unroll
            for (int j = 0; j < 8; j++)
                if (j < dd) tm[j] = fmaxf(tm[j], tm[j + dd]);
        float mx = fmaxf(tm[0], __shfl_xor(tm[0], 32, 64));
        bool small = __all(mx <= m + 44.0f);  // T13 defer-max
        float mnew = small ? m : fmaxf(m, mx);
#pragma unroll
        for (int j = 0; j < 16; j++)
            st[j] = __builtin_amdgcn_exp2f((st[j] - mnew) * KS2);
        float ts[16];
#pragma unroll
        for (int j = 0; j < 16; j++) ts[j] = st[j];
#pragma unroll
        for (int dd = 8; dd >= 1; dd >>= 1)
#pragma unroll
            for (int j = 0; j < 8; j++)
                if (j < dd) ts[j] += ts[j + dd];
        float ls = ts[0] + __shfl_xor(ts[0], 32, 64);
        if (small) {
            l += ls;
        } else {
            float sc = __builtin_amdgcn_exp2f((m - mnew) * KS2);
            l = l * sc + ls;
            o0 *= sc;
            o1 *= sc;
            m = mnew;
        }

        // ---- in-register P repack (4 shfl) + PV ----
#pragma unroll
        for (int ks = 0; ks < 2; ks++) {
            unsigned int a0 = pack_bf16(st[8 * ks + 0], st[8 * ks + 1]);
            unsigned int a1 = pack_bf16(st[8 * ks + 2], st[8 * ks + 3]);
            unsigned int b0 = pack_bf16(st[8 * ks + 4], st[8 * ks + 5]);
            unsigned int b1 = pack_bf16(st[8 * ks + 6], st[8 * ks + 7]);
            unsigned int y0 = lg2 ? a0 : b0;
            unsigned int y1 = lg2 ? a1 : b1;
            unsigned int p0 = __shfl_xor(y0, 32, 64);
            unsigned int p1 = __shfl_xor(y1, 32, 64);
            union { unsigned int u[4]; bf16x8 v; } pf;
            pf.u[0] = lg2 ? p0 : a0;
            pf.u[1] = lg2 ? p1 : a1;
            pf.u[2] = lg2 ? b0 : p0;
            pf.u[3] = lg2 ? b1 : p1;
            __builtin_amdgcn_s_setprio(1);
            o0 = mfma32(vf[ks * 2 + 0], pf.v, o0);
            o1 = mfma32(vf[ks * 2 + 1], pf.v, o1);
            __builtin_amdgcn_s_setprio(0);
        }
    }

    __syncthreads();  // waves done before combine staging

    // ---- 4-way combine: waves 1..3 stage (o,m,l); wave 0 merges ----
    if (w != 0) {
        float* SCw = (float*)(smem + (w - 1) * 8448);
#pragma unroll
        for (int j = 0; j < 16; j++) {
            int dl = (j & 3) + 8 * (j >> 2) + 4 * lg2;
            SCw[dl * 32 + l31] = o0[j];
            SCw[(32 + dl) * 32 + l31] = o1[j];
        }
        if (lg2 == 0) {
            SCw[2048 + l31] = m;
            SCw[2048 + 32 + l31] = l;
        }
    }
    __syncthreads();
    if (w == 0) {
        float* SC1 = (float*)(smem + 0);
        float* SC2 = (float*)(smem + 8448);
        float* SC3 = (float*)(smem + 16896);
        __hip_bfloat16* OL = (__hip_bfloat16*)(smem + 25344);
        float m1 = SC1[2048 + l31], l1 = SC1[2048 + 32 + l31];
        float m2 = SC2[2048 + l31], l2 = SC2[2048 + 32 + l31];
        float m3 = SC3[2048 + l31], l3 = SC3[2048 + 32 + l31];
        float M = fmaxf(fmaxf(m, m1), fmaxf(m2, m3));
        float e0 = __builtin_amdgcn_exp2f((m - M) * KS2);
        float e1 = __builtin_amdgcn_exp2f((m1 - M) * KS2);
        float e2 = __builtin_amdgcn_exp2f((m2 - M) * KS2);
        float e3 = __builtin_amdgcn_exp2f((m3 - M) * KS2);
        float L = l * e0 + l1 * e1 + l2 * e2 + l3 * e3;
        float linv = 1.0f / L;
#pragma unroll
        for (int od = 0; od < 2; od++) {
#pragma unroll
            for (int g = 0; g < 4; g++) {
                int dbase = od * 32 + 8 * g + 4 * lg2;
                ushort4 w4;
#pragma unroll
                for (int r = 0; r < 4; r++) {
                    int d = dbase + r;
                    float self = od ? o1[4 * g + r] : o0[4 * g + r];
                    float v = self * e0 + SC1[d * 32 + l31] * e1 +
                              SC2[d * 32 + l31] * e2 + SC3[d * 32 + l31] * e3;
                    v *= linv;
                    ((unsigned short*)&w4)[r] = f2bf_bits(v);
                }
                *reinterpret_cast<ushort4*>(&OL[l31 * 72 + dbase]) = w4;
            }
        }
    }
    __syncthreads();
    // coalesced store: 256 threads cover 32 q x 64 d
    {
        __hip_bfloat16* OL = (__hip_bfloat16*)(smem + 25344);
        int r = tid >> 3, c = (tid & 7) * 8;
        __hip_bfloat16* dst = AO + (size_t)(bbase + q0 + r) * DMODEL + h * HDIM + c;
        *reinterpret_cast<uint4*>(dst) = *reinterpret_cast<const uint4*>(&OL[r * 72 + c]);
    }
}

// ---------------- launch ----------------

extern "C" void kernel_launch(void* const* d_in, const int* in_sizes, int n_in,
                              void* d_out, int out_size, void* d_ws, size_t ws_size,
                              hipStream_t stream) {
    const float* hidden = (const float*)d_in[0];   // [2,2048,768]
    const float* w_attn = (const float*)d_in[1];   // [768,2304]
    const float* b_attn = (const float*)d_in[2];   // [2304]
    const float* w_proj = (const float*)d_in[3];   // [768,768]
    const float* b_proj = (const float*)d_in[4];   // [768]
    float* out = (float*)d_out;                    // [2,2048,768]

    char* ws = (char*)d_ws;
    __hip_bfloat16* Xb  = (__hip_bfloat16*)(ws + 0);         // 4096*768*2 = 6291456
    __hip_bfloat16* Wta = (__hip_bfloat16*)(ws + 6291456);   // 2304*768*2
    __hip_bfloat16* Wtp = (__hip_bfloat16*)(ws + 9830400);   // 768*768*2
    __hip_bfloat16* Qpb = (__hip_bfloat16*)(ws + 11010048);  // 24*131072*2 = 6291456
    __hip_bfloat16* Kpb = (__hip_bfloat16*)(ws + 17301504);  // 6291456
    __hip_bfloat16* Vpb = (__hip_bfloat16*)(ws + 23592960);  // 6291456
    __hip_bfloat16* AO  = (__hip_bfloat16*)(ws + 29884416);  // 4096*768*2

    const int M = BATCH * SEQ;  // 4096

    f32_to_bf16_k<<<dim3(M * DMODEL / (256 * 4)), dim3(256), 0, stream>>>(hidden, Xb);
    transpose_f32_to_bf16<<<dim3(QKVD / 32, DMODEL / 32), dim3(256), 0, stream>>>(w_attn, Wta, DMODEL, QKVD);
    transpose_f32_to_bf16<<<dim3(DMODEL / 32, DMODEL / 32), dim3(256), 0, stream>>>(w_proj, Wtp, DMODEL, DMODEL);
    gemm_qkv<<<dim3(QKVD / 128, M / 128), dim3(256), 0, stream>>>(Xb, Wta, b_attn, Qpb, Kpb, Vpb, M, QKVD, DMODEL);
    flash_attn<<<dim3(1536), dim3(256), 0, stream>>>(Qpb, Kpb, Vpb, AO);
    gemm_bt<false><<<dim3(DMODEL / 128, M / 128), dim3(256), 0, stream>>>(AO, Wtp, b_proj, out, M, DMODEL, DMODEL, DMODEL);
}

// Round 15
// 86.709 us; speedup vs baseline: 1.2169x; 1.0187x over previous
//
#include <hip/hip_runtime.h>
#include <hip/hip_bf16.h>

// GPT-2 attention block: B=2, S=2048, D=768, H=12, hd=64
#define BATCH 2
#define SEQ   2048
#define DMODEL 768
#define NHEAD 12
#define HDIM  64
#define QKVD  2304   // 3*DMODEL

typedef __bf16 bf16x8 __attribute__((ext_vector_type(8)));
typedef float f32x4 __attribute__((ext_vector_type(4)));
typedef float f32x16 __attribute__((ext_vector_type(16)));

static __device__ inline f32x4 mfma16(bf16x8 a, bf16x8 b, f32x4 c) {
    return __builtin_amdgcn_mfma_f32_16x16x32_bf16(a, b, c, 0, 0, 0);
}
static __device__ inline f32x16 mfma32(bf16x8 a, bf16x8 b, f32x16 c) {
    return __builtin_amdgcn_mfma_f32_32x32x16_bf16(a, b, c, 0, 0, 0);
}

static __device__ inline unsigned short f2bf_bits(float f) {
    __hip_bfloat16 h = __float2bfloat16(f);
    return __builtin_bit_cast(unsigned short, h);
}
static __device__ inline unsigned int pack_bf16(float a, float b) {
    return (unsigned int)f2bf_bits(a) | ((unsigned int)f2bf_bits(b) << 16);
}

// async global->LDS, 16B per lane
static __device__ inline void gload16(const __hip_bfloat16* g, __hip_bfloat16* l) {
    __builtin_amdgcn_global_load_lds(
        (const __attribute__((address_space(1))) void*)g,
        (__attribute__((address_space(3))) void*)l, 16, 0, 0);
}

// ---------------- fused prep: hidden->bf16 + both weight transposes ----------------
// grid 5376 = [0,3072) convert | [3072,4800) w_attn 72x24 | [4800,5376) w_proj 24x24

__global__ __launch_bounds__(256) void prep_fused(const float* __restrict__ hidden,
                                                  __hip_bfloat16* __restrict__ Xb,
                                                  const float* __restrict__ w_attn,
                                                  __hip_bfloat16* __restrict__ Wta,
                                                  const float* __restrict__ w_proj,
                                                  __hip_bfloat16* __restrict__ Wtp) {
    __shared__ float t[32][33];
    int blk = blockIdx.x;
    if (blk < 3072) {
        int i = blk * 256 + threadIdx.x;
        float4 v = reinterpret_cast<const float4*>(hidden)[i];
        ushort4 o;
        o.x = f2bf_bits(v.x); o.y = f2bf_bits(v.y);
        o.z = f2bf_bits(v.z); o.w = f2bf_bits(v.w);
        reinterpret_cast<ushort4*>(Xb)[i] = o;
        return;
    }
    const float* in;
    __hip_bfloat16* out;
    int R, C, bx, by;
    if (blk < 4800) {
        int k = blk - 3072;
        in = w_attn; out = Wta; R = DMODEL; C = QKVD;
        bx = (k % 72) * 32; by = (k / 72) * 32;
    } else {
        int k = blk - 4800;
        in = w_proj; out = Wtp; R = DMODEL; C = DMODEL;
        bx = (k % 24) * 32; by = (k / 24) * 32;
    }
    int tx = threadIdx.x & 31, ty = threadIdx.x >> 5;
#pragma unroll
    for (int k = 0; k < 4; k++)
        t[ty + k * 8][tx] = in[(size_t)(by + ty + k * 8) * C + bx + tx];
    __syncthreads();
#pragma unroll
    for (int k = 0; k < 4; k++)
        out[(size_t)(bx + ty + k * 8) * R + by + tx] = __float2bfloat16(t[tx][ty + k * 8]);
}

// ---------------- QKV GEMM with packed-fragment epilogue (unchanged) ----------------

__global__ __launch_bounds__(256) void gemm_qkv(const __hip_bfloat16* __restrict__ A,
                                                const __hip_bfloat16* __restrict__ Bt,
                                                const float* __restrict__ bias,
                                                __hip_bfloat16* __restrict__ Qp,
                                                __hip_bfloat16* __restrict__ Kp,
                                                __hip_bfloat16* __restrict__ Vp,
                                                int M, int N, int K) {
    __shared__ __hip_bfloat16 Al[2][128 * 32];
    __shared__ __hip_bfloat16 Bl[2][128 * 32];

    int tid = threadIdx.x;
    int wid = tid >> 6;
    int lane = tid & 63;
    int lr = lane & 15;
    int lg = lane >> 4;
    int m0 = blockIdx.y * 128;
    int n0 = blockIdx.x * 128;
    int wm = (wid >> 1) * 64;
    int wn = (wid & 1) * 64;

    int srow = wid * 16 + (lane >> 2);
    int scol = (lane & 3) * 8;
    const __hip_bfloat16* ag = A + (size_t)(m0 + srow) * K + scol;
    const __hip_bfloat16* bg = Bt + (size_t)(n0 + srow) * K + scol;
    int lofs = wid * 512;

    f32x4 acc[4][4] = {};

    gload16(ag, &Al[0][lofs]);
    gload16(ag + (size_t)64 * K, &Al[0][lofs + 2048]);
    gload16(bg, &Bl[0][lofs]);
    gload16(bg + (size_t)64 * K, &Bl[0][lofs + 2048]);
    __syncthreads();

    int nk = K >> 5;
    for (int t = 0; t < nk; t++) {
        int cb = t & 1;
        if (t + 1 < nk) {
            int k0 = (t + 1) << 5;
            int nb = cb ^ 1;
            gload16(ag + k0, &Al[nb][lofs]);
            gload16(ag + (size_t)64 * K + k0, &Al[nb][lofs + 2048]);
            gload16(bg + k0, &Bl[nb][lofs]);
            gload16(bg + (size_t)64 * K + k0, &Bl[nb][lofs + 2048]);
        }

        bf16x8 af[4], bfr[4];
#pragma unroll
        for (int i = 0; i < 4; i++)
            af[i] = *reinterpret_cast<const bf16x8*>(&Al[cb][(wm + i * 16 + lr) * 32 + lg * 8]);
#pragma unroll
        for (int j = 0; j < 4; j++)
            bfr[j] = *reinterpret_cast<const bf16x8*>(&Bl[cb][(wn + j * 16 + lr) * 32 + lg * 8]);
#pragma unroll
        for (int i = 0; i < 4; i++)
#pragma unroll
            for (int j = 0; j < 4; j++)
                acc[i][j] = mfma16(af[i], bfr[j], acc[i][j]);
        __syncthreads();
    }

#pragma unroll
    for (int j = 0; j < 4; j++) {
        int col = n0 + wn + j * 16 + lr;
        float bv = bias[col];
        int reg = col / DMODEL;                 // 0=Q,1=K,2=V (uniform per j)
        int cm = col - reg * DMODEL;
        int h = cm >> 6;
        int dd = cm & 63;
        __hip_bfloat16* dstQK = (reg == 0) ? Qp : Kp;
        if (reg < 2) {
            int kd = dd >> 4, half = (dd >> 3) & 1, e = dd & 7;
            int tbase = (kd * 2 + half) * 32;
#pragma unroll
            for (int i = 0; i < 4; i++) {
#pragma unroll
                for (int r = 0; r < 4; r++) {
                    int row = m0 + wm + i * 16 + lg * 4 + r;
                    int bq = row >> 11, tok = row & 2047;
                    size_t off = (size_t)(bq * NHEAD + h) * 131072 + (size_t)(tok >> 5) * 2048
                               + (size_t)(tbase + (tok & 31)) * 8 + e;
                    dstQK[off] = __float2bfloat16(acc[i][j][r] + bv);
                }
            }
        } else {
            int dh = dd >> 5, l31v = dd & 31;
#pragma unroll
            for (int i = 0; i < 4; i++) {
                int row0 = m0 + wm + i * 16 + lg * 4;
                int bq = row0 >> 11, tok0 = row0 & 2047;
                int ks = (tok0 >> 4) & 1, half = (tok0 >> 3) & 1;
                size_t off = (size_t)(bq * NHEAD + h) * 131072 + (size_t)(tok0 >> 5) * 2048
                           + (size_t)((((ks * 2 + dh) * 2 + half) * 32) + l31v) * 8 + (tok0 & 7);
                ushort4 w4;
                w4.x = f2bf_bits(acc[i][j][0] + bv);
                w4.y = f2bf_bits(acc[i][j][1] + bv);
                w4.z = f2bf_bits(acc[i][j][2] + bv);
                w4.w = f2bf_bits(acc[i][j][3] + bv);
                *reinterpret_cast<ushort4*>(Vp + off) = w4;
            }
        }
    }
}

// ---------------- GEMM: single-barrier double-buffered staging (unchanged) ----------------

template <bool OUT_BF16>
__global__ __launch_bounds__(256) void gemm_bt(const __hip_bfloat16* __restrict__ A,
                                               const __hip_bfloat16* __restrict__ Bt,
                                               const float* __restrict__ bias,
                                               void* __restrict__ Cp,
                                               int M, int N, int K, int lda) {
    __shared__ __hip_bfloat16 Al[2][128 * 32];
    __shared__ __hip_bfloat16 Bl[2][128 * 32];

    int tid = threadIdx.x;
    int wid = tid >> 6;
    int lane = tid & 63;
    int lr = lane & 15;
    int lg = lane >> 4;
    int m0 = blockIdx.y * 128;
    int n0 = blockIdx.x * 128;
    int wm = (wid >> 1) * 64;
    int wn = (wid & 1) * 64;

    int srow = wid * 16 + (lane >> 2);
    int scol = (lane & 3) * 8;
    const __hip_bfloat16* ag = A + (size_t)(m0 + srow) * lda + scol;
    const __hip_bfloat16* bg = Bt + (size_t)(n0 + srow) * K + scol;
    int lofs = wid * 512;

    f32x4 acc[4][4] = {};

    gload16(ag, &Al[0][lofs]);
    gload16(ag + (size_t)64 * lda, &Al[0][lofs + 2048]);
    gload16(bg, &Bl[0][lofs]);
    gload16(bg + (size_t)64 * K, &Bl[0][lofs + 2048]);
    __syncthreads();

    int nk = K >> 5;
    for (int t = 0; t < nk; t++) {
        int cb = t & 1;
        if (t + 1 < nk) {
            int k0 = (t + 1) << 5;
            int nb = cb ^ 1;
            gload16(ag + k0, &Al[nb][lofs]);
            gload16(ag + (size_t)64 * lda + k0, &Al[nb][lofs + 2048]);
            gload16(bg + k0, &Bl[nb][lofs]);
            gload16(bg + (size_t)64 * K + k0, &Bl[nb][lofs + 2048]);
        }

        bf16x8 af[4], bfr[4];
#pragma unroll
        for (int i = 0; i < 4; i++)
            af[i] = *reinterpret_cast<const bf16x8*>(&Al[cb][(wm + i * 16 + lr) * 32 + lg * 8]);
#pragma unroll
        for (int j = 0; j < 4; j++)
            bfr[j] = *reinterpret_cast<const bf16x8*>(&Bl[cb][(wn + j * 16 + lr) * 32 + lg * 8]);
#pragma unroll
        for (int i = 0; i < 4; i++)
#pragma unroll
            for (int j = 0; j < 4; j++)
                acc[i][j] = mfma16(af[i], bfr[j], acc[i][j]);
        __syncthreads();
    }

#pragma unroll
    for (int i = 0; i < 4; i++) {
#pragma unroll
        for (int j = 0; j < 4; j++) {
            int col = n0 + wn + j * 16 + lr;
            float bv = bias[col];
#pragma unroll
            for (int r = 0; r < 4; r++) {
                int row = m0 + wm + i * 16 + lg * 4 + r;
                float v = acc[i][j][r] + bv;
                if (OUT_BF16)
                    ((__hip_bfloat16*)Cp)[(size_t)row * N + col] = __float2bfloat16(v);
                else
                    ((float*)Cp)[(size_t)row * N + col] = v;
            }
        }
    }
}

// ---------------- causal flash attention v15: low-register software pipeline ----------------
// v14 + reorder: per iter = softmax(st of tile t) -> repack to pfA/pfB (st dies) ->
// QK^T(t+1) reuses st's registers -> PV(t). The QK->softmax stall now hides behind
// PV + loop overhead. Only pfA/pfB (+8 regs) live across QK (v13's +48-reg spill avoided).

#define KS2 0.18033688f  // 0.125 * log2(e)

__global__ __launch_bounds__(256, 4) void flash_attn(const __hip_bfloat16* __restrict__ Qp,
                                                     const __hip_bfloat16* __restrict__ Kp,
                                                     const __hip_bfloat16* __restrict__ Vp,
                                                     __hip_bfloat16* __restrict__ AO) {
    // combine-only LDS: SC_w (w=1..3) at (w-1)*8448; OL at 25344 ([32 q][72 d] bf16)
    __shared__ __align__(16) char smem[30208];

    int tid = threadIdx.x;
    int w = tid >> 6;        // wave = kv quarter parity
    int lane = tid & 63;
    int l31 = lane & 31;
    int lg2 = lane >> 5;

    // block -> (xcd-chunked head, descending q-tile)
    int wg = blockIdx.x;
    int xcd = wg & 7;
    int slot = wg >> 3;          // 0..191
    int hsl = slot % 3;
    int qsl = slot / 3;          // 0..63
    int bh = xcd * 3 + hsl;
    int it = 63 - qsl;           // largest first
    int b = bh / NHEAD;
    int h = bh - b * NHEAD;
    int q0 = it * 32;
    int bbase = b * SEQ;

    // per-wave iteration count: kv quarters 32*(4t+w) <= q0
    int Tw = (it >= w) ? ((it - w) >> 2) + 1 : 0;

    const __hip_bfloat16* Kph = Kp + (size_t)bh * 131072;
    const __hip_bfloat16* Vph = Vp + (size_t)bh * 131072;

    // Q fragments: coalesced packed load (same layout as K)
    bf16x8 qf[4];
    {
        const __hip_bfloat16* qr = Qp + (size_t)bh * 131072 + (size_t)it * 2048 + l31 * 8;
#pragma unroll
        for (int kd = 0; kd < 4; kd++)
            qf[kd] = *reinterpret_cast<const bf16x8*>(qr + (kd * 2 + lg2) * 256);
    }

    f32x16 o0 = {}, o1 = {};
    float m = -3.0e38f, l = 0.f;

    bf16x8 kc[4];
    f32x16 st;

    // prologue: K frags + QK for quarter w; preload K for quarter w+4
    if (Tw > 0) {
        const __hip_bfloat16* kr = Kph + (size_t)w * 2048 + l31 * 8;
#pragma unroll
        for (int kd = 0; kd < 4; kd++)
            kc[kd] = *reinterpret_cast<const bf16x8*>(kr + (kd * 2 + lg2) * 256);
        __builtin_amdgcn_s_setprio(1);
        f32x16 s = {};
#pragma unroll
        for (int kd = 0; kd < 4; kd++)
            s = mfma32(kc[kd], qf[kd], s);
        __builtin_amdgcn_s_setprio(0);
        st = s;
        if (Tw > 1) {
            const __hip_bfloat16* kr2 = Kph + (size_t)(w + 4) * 2048 + l31 * 8;
#pragma unroll
            for (int kd = 0; kd < 4; kd++)
                kc[kd] = *reinterpret_cast<const bf16x8*>(kr2 + (kd * 2 + lg2) * 256);
        }
    }

    for (int t = 0; t < Tw; t++) {
        int qi = 4 * t + w;
        int kvbase = qi * 32;

        // ---- V^T fragments for tile t: coalesced, issued early ----
        const __hip_bfloat16* vr = Vph + (size_t)qi * 2048 + lg2 * 256 + l31 * 8;
        bf16x8 vf[4];
#pragma unroll
        for (int ks = 0; ks < 2; ks++)
#pragma unroll
            for (int dh = 0; dh < 2; dh++)
                vf[ks * 2 + dh] = *reinterpret_cast<const bf16x8*>(vr + (ks * 2 + dh) * 512);

        if (kvbase == q0) {  // diagonal subtile: causal mask
#pragma unroll
            for (int j = 0; j < 16; j++) {
                int kvl = (j & 3) + 8 * (j >> 2) + 4 * lg2;
                if (kvl > l31) st[j] = -3.0e38f;
            }
        }
        // ---- online softmax on st (tile t) ----
        float tm[16];
#pragma unroll
        for (int j = 0; j < 16; j++) tm[j] = st[j];
#pragma unroll
        for (int dd = 8; dd >= 1; dd >>= 1)
#pragma unroll
            for (int j = 0; j < 8; j++)
                if (j < dd) tm[j] = fmaxf(tm[j], tm[j + dd]);
        float mx = fmaxf(tm[0], __shfl_xor(tm[0], 32, 64));
        bool small = __all(mx <= m + 44.0f);  // T13 defer-max
        float mnew = small ? m : fmaxf(m, mx);
#pragma unroll
        for (int j = 0; j < 16; j++)
            st[j] = __builtin_amdgcn_exp2f((st[j] - mnew) * KS2);
        float ts[16];
#pragma unroll
        for (int j = 0; j < 16; j++) ts[j] = st[j];
#pragma unroll
        for (int dd = 8; dd >= 1; dd >>= 1)
#pragma unroll
            for (int j = 0; j < 8; j++)
                if (j < dd) ts[j] += ts[j + dd];
        float ls = ts[0] + __shfl_xor(ts[0], 32, 64);
        if (small) {
            l += ls;
        } else {
            float sc = __builtin_amdgcn_exp2f((m - mnew) * KS2);
            l = l * sc + ls;
            o0 *= sc;
            o1 *= sc;
            m = mnew;
        }

        // ---- repack st -> pfA (ks=0), pfB (ks=1); st dead after ----
        union PF { unsigned int u[4]; bf16x8 v; };
        PF pfA, pfB;
        {
            unsigned int a0 = pack_bf16(st[0], st[1]);
            unsigned int a1 = pack_bf16(st[2], st[3]);
            unsigned int b0 = pack_bf16(st[4], st[5]);
            unsigned int b1 = pack_bf16(st[6], st[7]);
            unsigned int y0 = lg2 ? a0 : b0;
            unsigned int y1 = lg2 ? a1 : b1;
            unsigned int p0 = __shfl_xor(y0, 32, 64);
            unsigned int p1 = __shfl_xor(y1, 32, 64);
            pfA.u[0] = lg2 ? p0 : a0;
            pfA.u[1] = lg2 ? p1 : a1;
            pfA.u[2] = lg2 ? b0 : p0;
            pfA.u[3] = lg2 ? b1 : p1;
        }
        {
            unsigned int a0 = pack_bf16(st[8], st[9]);
            unsigned int a1 = pack_bf16(st[10], st[11]);
            unsigned int b0 = pack_bf16(st[12], st[13]);
            unsigned int b1 = pack_bf16(st[14], st[15]);
            unsigned int y0 = lg2 ? a0 : b0;
            unsigned int y1 = lg2 ? a1 : b1;
            unsigned int p0 = __shfl_xor(y0, 32, 64);
            unsigned int p1 = __shfl_xor(y1, 32, 64);
            pfB.u[0] = lg2 ? p0 : a0;
            pfB.u[1] = lg2 ? p1 : a1;
            pfB.u[2] = lg2 ? b0 : p0;
            pfB.u[3] = lg2 ? b1 : p1;
        }

        // ---- QK^T(t+1) into st's registers (issued before PV -> stall hidden) ----
        if (t + 1 < Tw) {
            __builtin_amdgcn_s_setprio(1);
            f32x16 s = {};
#pragma unroll
            for (int kd = 0; kd < 4; kd++)
                s = mfma32(kc[kd], qf[kd], s);
            __builtin_amdgcn_s_setprio(0);
            st = s;
            if (t + 2 < Tw) {  // K frags for t+2
                const __hip_bfloat16* kr = Kph + (size_t)(qi + 8) * 2048 + l31 * 8;
#pragma unroll
                for (int kd = 0; kd < 4; kd++)
                    kc[kd] = *reinterpret_cast<const bf16x8*>(kr + (kd * 2 + lg2) * 256);
            }
        }

        // ---- PV(t) ----
        __builtin_amdgcn_s_setprio(1);
        o0 = mfma32(vf[0], pfA.v, o0);
        o1 = mfma32(vf[1], pfA.v, o1);
        o0 = mfma32(vf[2], pfB.v, o0);
        o1 = mfma32(vf[3], pfB.v, o1);
        __builtin_amdgcn_s_setprio(0);
    }

    __syncthreads();  // waves done before combine staging

    // ---- 4-way combine: waves 1..3 stage (o,m,l); wave 0 merges ----
    if (w != 0) {
        float* SCw = (float*)(smem + (w - 1) * 8448);
#pragma unroll
        for (int j = 0; j < 16; j++) {
            int dl = (j & 3) + 8 * (j >> 2) + 4 * lg2;
            SCw[dl * 32 + l31] = o0[j];
            SCw[(32 + dl) * 32 + l31] = o1[j];
        }
        if (lg2 == 0) {
            SCw[2048 + l31] = m;
            SCw[2048 + 32 + l31] = l;
        }
    }
    __syncthreads();
    if (w == 0) {
        float* SC1 = (float*)(smem + 0);
        float* SC2 = (float*)(smem + 8448);
        float* SC3 = (float*)(smem + 16896);
        __hip_bfloat16* OL = (__hip_bfloat16*)(smem + 25344);
        float m1 = SC1[2048 + l31], l1 = SC1[2048 + 32 + l31];
        float m2 = SC2[2048 + l31], l2 = SC2[2048 + 32 + l31];
        float m3 = SC3[2048 + l31], l3 = SC3[2048 + 32 + l31];
        float M = fmaxf(fmaxf(m, m1), fmaxf(m2, m3));
        float e0 = __builtin_amdgcn_exp2f((m - M) * KS2);
        float e1 = __builtin_amdgcn_exp2f((m1 - M) * KS2);
        float e2 = __builtin_amdgcn_exp2f((m2 - M) * KS2);
        float e3 = __builtin_amdgcn_exp2f((m3 - M) * KS2);
        float L = l * e0 + l1 * e1 + l2 * e2 + l3 * e3;
        float linv = 1.0f / L;
#pragma unroll
        for (int od = 0; od < 2; od++) {
#pragma unroll
            for (int g = 0; g < 4; g++) {
                int dbase = od * 32 + 8 * g + 4 * lg2;
                ushort4 w4;
#pragma unroll
                for (int r = 0; r < 4; r++) {
                    int d = dbase + r;
                    float self = od ? o1[4 * g + r] : o0[4 * g + r];
                    float v = self * e0 + SC1[d * 32 + l31] * e1 +
                              SC2[d * 32 + l31] * e2 + SC3[d * 32 + l31] * e3;
                    v *= linv;
                    ((unsigned short*)&w4)[r] = f2bf_bits(v);
                }
                *reinterpret_cast<ushort4*>(&OL[l31 * 72 + dbase]) = w4;
            }
        }
    }
    __syncthreads();
    // coalesced store: 256 threads cover 32 q x 64 d
    {
        __hip_bfloat16* OL = (__hip_bfloat16*)(smem + 25344);
        int r = tid >> 3, c = (tid & 7) * 8;
        __hip_bfloat16* dst = AO + (size_t)(bbase + q0 + r) * DMODEL + h * HDIM + c;
        *reinterpret_cast<uint4*>(dst) = *reinterpret_cast<const uint4*>(&OL[r * 72 + c]);
    }
}

// ---------------- launch ----------------

extern "C" void kernel_launch(void* const* d_in, const int* in_sizes, int n_in,
                              void* d_out, int out_size, void* d_ws, size_t ws_size,
                              hipStream_t stream) {
    const float* hidden = (const float*)d_in[0];   // [2,2048,768]
    const float* w_attn = (const float*)d_in[1];   // [768,2304]
    const float* b_attn = (const float*)d_in[2];   // [2304]
    const float* w_proj = (const float*)d_in[3];   // [768,768]
    const float* b_proj = (const float*)d_in[4];   // [768]
    float* out = (float*)d_out;                    // [2,2048,768]

    char* ws = (char*)d_ws;
    __hip_bfloat16* Xb  = (__hip_bfloat16*)(ws + 0);         // 4096*768*2 = 6291456
    __hip_bfloat16* Wta = (__hip_bfloat16*)(ws + 6291456);   // 2304*768*2
    __hip_bfloat16* Wtp = (__hip_bfloat16*)(ws + 9830400);   // 768*768*2
    __hip_bfloat16* Qpb = (__hip_bfloat16*)(ws + 11010048);  // 24*131072*2 = 6291456
    __hip_bfloat16* Kpb = (__hip_bfloat16*)(ws + 17301504);  // 6291456
    __hip_bfloat16* Vpb = (__hip_bfloat16*)(ws + 23592960);  // 6291456
    __hip_bfloat16* AO  = (__hip_bfloat16*)(ws + 29884416);  // 4096*768*2

    const int M = BATCH * SEQ;  // 4096

    prep_fused<<<dim3(5376), dim3(256), 0, stream>>>(hidden, Xb, w_attn, Wta, w_proj, Wtp);
    gemm_qkv<<<dim3(QKVD / 128, M / 128), dim3(256), 0, stream>>>(Xb, Wta, b_attn, Qpb, Kpb, Vpb, M, QKVD, DMODEL);
    flash_attn<<<dim3(1536), dim3(256), 0, stream>>>(Qpb, Kpb, Vpb, AO);
    gemm_bt<false><<<dim3(DMODEL / 128, M / 128), dim3(256), 0, stream>>>(AO, Wtp, b_proj, out, M, DMODEL, DMODEL, DMODEL);
}

// Round 16
// 80.873 us; speedup vs baseline: 1.3048x; 1.0722x over previous
//
#include <hip/hip_runtime.h>
#include <hip/hip_bf16.h>

// GPT-2 attention block: B=2, S=2048, D=768, H=12, hd=64
#define BATCH 2
#define SEQ   2048
#define DMODEL 768
#define NHEAD 12
#define HDIM  64
#define QKVD  2304   // 3*DMODEL

typedef __bf16 bf16x8 __attribute__((ext_vector_type(8)));
typedef float f32x4 __attribute__((ext_vector_type(4)));
typedef float f32x16 __attribute__((ext_vector_type(16)));

static __device__ inline f32x4 mfma16(bf16x8 a, bf16x8 b, f32x4 c) {
    return __builtin_amdgcn_mfma_f32_16x16x32_bf16(a, b, c, 0, 0, 0);
}
static __device__ inline f32x16 mfma32(bf16x8 a, bf16x8 b, f32x16 c) {
    return __builtin_amdgcn_mfma_f32_32x32x16_bf16(a, b, c, 0, 0, 0);
}

static __device__ inline unsigned short f2bf_bits(float f) {
    __hip_bfloat16 h = __float2bfloat16(f);
    return __builtin_bit_cast(unsigned short, h);
}
static __device__ inline unsigned int pack_bf16(float a, float b) {
    return (unsigned int)f2bf_bits(a) | ((unsigned int)f2bf_bits(b) << 16);
}

// async global->LDS, 16B per lane
static __device__ inline void gload16(const __hip_bfloat16* g, __hip_bfloat16* l) {
    __builtin_amdgcn_global_load_lds(
        (const __attribute__((address_space(1))) void*)g,
        (__attribute__((address_space(3))) void*)l, 16, 0, 0);
}

// ---------------- fused prep: hidden->bf16 + both weight transposes ----------------
// grid 5376 = [0,3072) convert | [3072,4800) w_attn 72x24 | [4800,5376) w_proj 24x24

__global__ __launch_bounds__(256) void prep_fused(const float* __restrict__ hidden,
                                                  __hip_bfloat16* __restrict__ Xb,
                                                  const float* __restrict__ w_attn,
                                                  __hip_bfloat16* __restrict__ Wta,
                                                  const float* __restrict__ w_proj,
                                                  __hip_bfloat16* __restrict__ Wtp) {
    __shared__ float t[32][33];
    int blk = blockIdx.x;
    if (blk < 3072) {
        int i = blk * 256 + threadIdx.x;
        float4 v = reinterpret_cast<const float4*>(hidden)[i];
        ushort4 o;
        o.x = f2bf_bits(v.x); o.y = f2bf_bits(v.y);
        o.z = f2bf_bits(v.z); o.w = f2bf_bits(v.w);
        reinterpret_cast<ushort4*>(Xb)[i] = o;
        return;
    }
    const float* in;
    __hip_bfloat16* out;
    int R, C, bx, by;
    if (blk < 4800) {
        int k = blk - 3072;
        in = w_attn; out = Wta; R = DMODEL; C = QKVD;
        bx = (k % 72) * 32; by = (k / 72) * 32;
    } else {
        int k = blk - 4800;
        in = w_proj; out = Wtp; R = DMODEL; C = DMODEL;
        bx = (k % 24) * 32; by = (k / 24) * 32;
    }
    int tx = threadIdx.x & 31, ty = threadIdx.x >> 5;
#pragma unroll
    for (int k = 0; k < 4; k++)
        t[ty + k * 8][tx] = in[(size_t)(by + ty + k * 8) * C + bx + tx];
    __syncthreads();
#pragma unroll
    for (int k = 0; k < 4; k++)
        out[(size_t)(bx + ty + k * 8) * R + by + tx] = __float2bfloat16(t[tx][ty + k * 8]);
}

// ---------------- QKV GEMM with packed-fragment epilogue + XCD-chunked swizzle ----------------

__global__ __launch_bounds__(256) void gemm_qkv(const __hip_bfloat16* __restrict__ A,
                                                const __hip_bfloat16* __restrict__ Bt,
                                                const float* __restrict__ bias,
                                                __hip_bfloat16* __restrict__ Qp,
                                                __hip_bfloat16* __restrict__ Kp,
                                                __hip_bfloat16* __restrict__ Vp,
                                                int M, int N, int K) {
    __shared__ __hip_bfloat16 Al[2][128 * 32];
    __shared__ __hip_bfloat16 Bl[2][128 * 32];

    int tid = threadIdx.x;
    int wid = tid >> 6;
    int lane = tid & 63;
    int lr = lane & 15;
    int lg = lane >> 4;
    // XCD-chunked bijective swizzle: 576 blocks, 8 XCDs x 72 (4 A-panels + all B-panels ~ 4.25MB/L2)
    int wg = blockIdx.x;
    int swz = (wg & 7) * 72 + (wg >> 3);
    int bxq = swz % 18;          // N-block
    int byq = swz / 18;          // M-block
    int m0 = byq * 128;
    int n0 = bxq * 128;
    int wm = (wid >> 1) * 64;
    int wn = (wid & 1) * 64;

    int srow = wid * 16 + (lane >> 2);
    int scol = (lane & 3) * 8;
    const __hip_bfloat16* ag = A + (size_t)(m0 + srow) * K + scol;
    const __hip_bfloat16* bg = Bt + (size_t)(n0 + srow) * K + scol;
    int lofs = wid * 512;

    f32x4 acc[4][4] = {};

    gload16(ag, &Al[0][lofs]);
    gload16(ag + (size_t)64 * K, &Al[0][lofs + 2048]);
    gload16(bg, &Bl[0][lofs]);
    gload16(bg + (size_t)64 * K, &Bl[0][lofs + 2048]);
    __syncthreads();

    int nk = K >> 5;
    for (int t = 0; t < nk; t++) {
        int cb = t & 1;
        if (t + 1 < nk) {
            int k0 = (t + 1) << 5;
            int nb = cb ^ 1;
            gload16(ag + k0, &Al[nb][lofs]);
            gload16(ag + (size_t)64 * K + k0, &Al[nb][lofs + 2048]);
            gload16(bg + k0, &Bl[nb][lofs]);
            gload16(bg + (size_t)64 * K + k0, &Bl[nb][lofs + 2048]);
        }

        bf16x8 af[4], bfr[4];
#pragma unroll
        for (int i = 0; i < 4; i++)
            af[i] = *reinterpret_cast<const bf16x8*>(&Al[cb][(wm + i * 16 + lr) * 32 + lg * 8]);
#pragma unroll
        for (int j = 0; j < 4; j++)
            bfr[j] = *reinterpret_cast<const bf16x8*>(&Bl[cb][(wn + j * 16 + lr) * 32 + lg * 8]);
#pragma unroll
        for (int i = 0; i < 4; i++)
#pragma unroll
            for (int j = 0; j < 4; j++)
                acc[i][j] = mfma16(af[i], bfr[j], acc[i][j]);
        __syncthreads();
    }

#pragma unroll
    for (int j = 0; j < 4; j++) {
        int col = n0 + wn + j * 16 + lr;
        float bv = bias[col];
        int reg = col / DMODEL;                 // 0=Q,1=K,2=V (uniform per j)
        int cm = col - reg * DMODEL;
        int h = cm >> 6;
        int dd = cm & 63;
        __hip_bfloat16* dstQK = (reg == 0) ? Qp : Kp;
        if (reg < 2) {
            int kd = dd >> 4, half = (dd >> 3) & 1, e = dd & 7;
            int tbase = (kd * 2 + half) * 32;
#pragma unroll
            for (int i = 0; i < 4; i++) {
#pragma unroll
                for (int r = 0; r < 4; r++) {
                    int row = m0 + wm + i * 16 + lg * 4 + r;
                    int bq = row >> 11, tok = row & 2047;
                    size_t off = (size_t)(bq * NHEAD + h) * 131072 + (size_t)(tok >> 5) * 2048
                               + (size_t)(tbase + (tok & 31)) * 8 + e;
                    dstQK[off] = __float2bfloat16(acc[i][j][r] + bv);
                }
            }
        } else {
            int dh = dd >> 5, l31v = dd & 31;
#pragma unroll
            for (int i = 0; i < 4; i++) {
                int row0 = m0 + wm + i * 16 + lg * 4;
                int bq = row0 >> 11, tok0 = row0 & 2047;
                int ks = (tok0 >> 4) & 1, half = (tok0 >> 3) & 1;
                size_t off = (size_t)(bq * NHEAD + h) * 131072 + (size_t)(tok0 >> 5) * 2048
                           + (size_t)((((ks * 2 + dh) * 2 + half) * 32) + l31v) * 8 + (tok0 & 7);
                ushort4 w4;
                w4.x = f2bf_bits(acc[i][j][0] + bv);
                w4.y = f2bf_bits(acc[i][j][1] + bv);
                w4.z = f2bf_bits(acc[i][j][2] + bv);
                w4.w = f2bf_bits(acc[i][j][3] + bv);
                *reinterpret_cast<ushort4*>(Vp + off) = w4;
            }
        }
    }
}

// ---------------- proj GEMM: 64x64 tiles, mfma32, grid 768 = 3 blocks/CU uniform ----------------
// out[M][768] f32 = AO[M][768] @ Wtp[768][768]^T + bias. Block 256 thr = 4 waves (2x2),
// each wave one 32x32 mfma32 acc. BK=32 dbuf staging via gload16 (1 call/operand/step).
// mfma32 layouts: A-op row=l31, B-op col=l31, k=lg2*8+i; C/D row=(j&3)+8*(j>>2)+4*lg2.

__global__ __launch_bounds__(256) void gemm_proj64(const __hip_bfloat16* __restrict__ A,
                                                   const __hip_bfloat16* __restrict__ Bt,
                                                   const float* __restrict__ bias,
                                                   float* __restrict__ out,
                                                   int M, int N, int K) {
    __shared__ __hip_bfloat16 Al[2][64 * 32];
    __shared__ __hip_bfloat16 Bl[2][64 * 32];

    int tid = threadIdx.x;
    int wid = tid >> 6;
    int lane = tid & 63;
    int l31 = lane & 31;
    int lg2 = lane >> 5;
    int wr = wid >> 1;           // m sub-tile
    int wc = wid & 1;            // n sub-tile

    // XCD-chunked bijective swizzle: 768 = 8 x 96
    int wg = blockIdx.x;
    int swz = (wg & 7) * 96 + (wg >> 3);
    int bx = swz % 12;           // N-block (0..11)
    int by = swz / 12;           // M-block (0..63)
    int m0 = by * 64;
    int n0 = bx * 64;

    int srow = tid >> 2;         // 0..63
    int scol = (tid & 3) * 8;
    const __hip_bfloat16* ag = A + (size_t)(m0 + srow) * K + scol;
    const __hip_bfloat16* bg = Bt + (size_t)(n0 + srow) * K + scol;
    int lofs = wid * 512;        // wave-uniform LDS base (elements)

    f32x16 acc = {};

    gload16(ag, &Al[0][lofs]);
    gload16(bg, &Bl[0][lofs]);
    __syncthreads();

    int nk = K >> 5;             // 24
    for (int t = 0; t < nk; t++) {
        int cb = t & 1;
        if (t + 1 < nk) {
            int k0 = (t + 1) << 5;
            int nb = cb ^ 1;
            gload16(ag + k0, &Al[nb][lofs]);
            gload16(bg + k0, &Bl[nb][lofs]);
        }
#pragma unroll
        for (int ks = 0; ks < 2; ks++) {
            bf16x8 af = *reinterpret_cast<const bf16x8*>(
                &Al[cb][(32 * wr + l31) * 32 + ks * 16 + lg2 * 8]);
            bf16x8 bfr = *reinterpret_cast<const bf16x8*>(
                &Bl[cb][(32 * wc + l31) * 32 + ks * 16 + lg2 * 8]);
            acc = mfma32(af, bfr, acc);
        }
        __syncthreads();
    }

    // epilogue: row=(j&3)+8*(j>>2)+4*lg2 (m-local), col=l31 (n-local); f32 coalesced
    int col = n0 + 32 * wc + l31;
    float bv = bias[col];
#pragma unroll
    for (int j = 0; j < 16; j++) {
        int row = m0 + 32 * wr + (j & 3) + 8 * (j >> 2) + 4 * lg2;
        out[(size_t)row * N + col] = acc[j] + bv;
    }
}

// ---------------- causal flash attention v15 (unchanged) ----------------

#define KS2 0.18033688f  // 0.125 * log2(e)

__global__ __launch_bounds__(256, 4) void flash_attn(const __hip_bfloat16* __restrict__ Qp,
                                                     const __hip_bfloat16* __restrict__ Kp,
                                                     const __hip_bfloat16* __restrict__ Vp,
                                                     __hip_bfloat16* __restrict__ AO) {
    // combine-only LDS: SC_w (w=1..3) at (w-1)*8448; OL at 25344 ([32 q][72 d] bf16)
    __shared__ __align__(16) char smem[30208];

    int tid = threadIdx.x;
    int w = tid >> 6;        // wave = kv quarter parity
    int lane = tid & 63;
    int l31 = lane & 31;
    int lg2 = lane >> 5;

    // block -> (xcd-chunked head, descending q-tile)
    int wg = blockIdx.x;
    int xcd = wg & 7;
    int slot = wg >> 3;          // 0..191
    int hsl = slot % 3;
    int qsl = slot / 3;          // 0..63
    int bh = xcd * 3 + hsl;
    int it = 63 - qsl;           // largest first
    int b = bh / NHEAD;
    int h = bh - b * NHEAD;
    int q0 = it * 32;
    int bbase = b * SEQ;

    // per-wave iteration count: kv quarters 32*(4t+w) <= q0
    int Tw = (it >= w) ? ((it - w) >> 2) + 1 : 0;

    const __hip_bfloat16* Kph = Kp + (size_t)bh * 131072;
    const __hip_bfloat16* Vph = Vp + (size_t)bh * 131072;

    // Q fragments: coalesced packed load (same layout as K)
    bf16x8 qf[4];
    {
        const __hip_bfloat16* qr = Qp + (size_t)bh * 131072 + (size_t)it * 2048 + l31 * 8;
#pragma unroll
        for (int kd = 0; kd < 4; kd++)
            qf[kd] = *reinterpret_cast<const bf16x8*>(qr + (kd * 2 + lg2) * 256);
    }

    f32x16 o0 = {}, o1 = {};
    float m = -3.0e38f, l = 0.f;

    bf16x8 kc[4];
    f32x16 st;

    // prologue: K frags + QK for quarter w; preload K for quarter w+4
    if (Tw > 0) {
        const __hip_bfloat16* kr = Kph + (size_t)w * 2048 + l31 * 8;
#pragma unroll
        for (int kd = 0; kd < 4; kd++)
            kc[kd] = *reinterpret_cast<const bf16x8*>(kr + (kd * 2 + lg2) * 256);
        __builtin_amdgcn_s_setprio(1);
        f32x16 s = {};
#pragma unroll
        for (int kd = 0; kd < 4; kd++)
            s = mfma32(kc[kd], qf[kd], s);
        __builtin_amdgcn_s_setprio(0);
        st = s;
        if (Tw > 1) {
            const __hip_bfloat16* kr2 = Kph + (size_t)(w + 4) * 2048 + l31 * 8;
#pragma unroll
            for (int kd = 0; kd < 4; kd++)
                kc[kd] = *reinterpret_cast<const bf16x8*>(kr2 + (kd * 2 + lg2) * 256);
        }
    }

    for (int t = 0; t < Tw; t++) {
        int qi = 4 * t + w;
        int kvbase = qi * 32;

        // ---- V^T fragments for tile t: coalesced, issued early ----
        const __hip_bfloat16* vr = Vph + (size_t)qi * 2048 + lg2 * 256 + l31 * 8;
        bf16x8 vf[4];
#pragma unroll
        for (int ks = 0; ks < 2; ks++)
#pragma unroll
            for (int dh = 0; dh < 2; dh++)
                vf[ks * 2 + dh] = *reinterpret_cast<const bf16x8*>(vr + (ks * 2 + dh) * 512);

        if (kvbase == q0) {  // diagonal subtile: causal mask
#pragma unroll
            for (int j = 0; j < 16; j++) {
                int kvl = (j & 3) + 8 * (j >> 2) + 4 * lg2;
                if (kvl > l31) st[j] = -3.0e38f;
            }
        }
        // ---- online softmax on st (tile t) ----
        float tm[16];
#pragma unroll
        for (int j = 0; j < 16; j++) tm[j] = st[j];
#pragma unroll
        for (int dd = 8; dd >= 1; dd >>= 1)
#pragma unroll
            for (int j = 0; j < 8; j++)
                if (j < dd) tm[j] = fmaxf(tm[j], tm[j + dd]);
        float mx = fmaxf(tm[0], __shfl_xor(tm[0], 32, 64));
        bool small = __all(mx <= m + 44.0f);  // T13 defer-max
        float mnew = small ? m : fmaxf(m, mx);
#pragma unroll
        for (int j = 0; j < 16; j++)
            st[j] = __builtin_amdgcn_exp2f((st[j] - mnew) * KS2);
        float ts[16];
#pragma unroll
        for (int j = 0; j < 16; j++) ts[j] = st[j];
#pragma unroll
        for (int dd = 8; dd >= 1; dd >>= 1)
#pragma unroll
            for (int j = 0; j < 8; j++)
                if (j < dd) ts[j] += ts[j + dd];
        float ls = ts[0] + __shfl_xor(ts[0], 32, 64);
        if (small) {
            l += ls;
        } else {
            float sc = __builtin_amdgcn_exp2f((m - mnew) * KS2);
            l = l * sc + ls;
            o0 *= sc;
            o1 *= sc;
            m = mnew;
        }

        // ---- repack st -> pfA (ks=0), pfB (ks=1); st dead after ----
        union PF { unsigned int u[4]; bf16x8 v; };
        PF pfA, pfB;
        {
            unsigned int a0 = pack_bf16(st[0], st[1]);
            unsigned int a1 = pack_bf16(st[2], st[3]);
            unsigned int b0 = pack_bf16(st[4], st[5]);
            unsigned int b1 = pack_bf16(st[6], st[7]);
            unsigned int y0 = lg2 ? a0 : b0;
            unsigned int y1 = lg2 ? a1 : b1;
            unsigned int p0 = __shfl_xor(y0, 32, 64);
            unsigned int p1 = __shfl_xor(y1, 32, 64);
            pfA.u[0] = lg2 ? p0 : a0;
            pfA.u[1] = lg2 ? p1 : a1;
            pfA.u[2] = lg2 ? b0 : p0;
            pfA.u[3] = lg2 ? b1 : p1;
        }
        {
            unsigned int a0 = pack_bf16(st[8], st[9]);
            unsigned int a1 = pack_bf16(st[10], st[11]);
            unsigned int b0 = pack_bf16(st[12], st[13]);
            unsigned int b1 = pack_bf16(st[14], st[15]);
            unsigned int y0 = lg2 ? a0 : b0;
            unsigned int y1 = lg2 ? a1 : b1;
            unsigned int p0 = __shfl_xor(y0, 32, 64);
            unsigned int p1 = __shfl_xor(y1, 32, 64);
            pfB.u[0] = lg2 ? p0 : a0;
            pfB.u[1] = lg2 ? p1 : a1;
            pfB.u[2] = lg2 ? b0 : p0;
            pfB.u[3] = lg2 ? b1 : p1;
        }

        // ---- QK^T(t+1) into st's registers (issued before PV -> stall hidden) ----
        if (t + 1 < Tw) {
            __builtin_amdgcn_s_setprio(1);
            f32x16 s = {};
#pragma unroll
            for (int kd = 0; kd < 4; kd++)
                s = mfma32(kc[kd], qf[kd], s);
            __builtin_amdgcn_s_setprio(0);
            st = s;
            if (t + 2 < Tw) {  // K frags for t+2
                const __hip_bfloat16* kr = Kph + (size_t)(qi + 8) * 2048 + l31 * 8;
#pragma unroll
                for (int kd = 0; kd < 4; kd++)
                    kc[kd] = *reinterpret_cast<const bf16x8*>(kr + (kd * 2 + lg2) * 256);
            }
        }

        // ---- PV(t) ----
        __builtin_amdgcn_s_setprio(1);
        o0 = mfma32(vf[0], pfA.v, o0);
        o1 = mfma32(vf[1], pfA.v, o1);
        o0 = mfma32(vf[2], pfB.v, o0);
        o1 = mfma32(vf[3], pfB.v, o1);
        __builtin_amdgcn_s_setprio(0);
    }

    __syncthreads();  // waves done before combine staging

    // ---- 4-way combine: waves 1..3 stage (o,m,l); wave 0 merges ----
    if (w != 0) {
        float* SCw = (float*)(smem + (w - 1) * 8448);
#pragma unroll
        for (int j = 0; j < 16; j++) {
            int dl = (j & 3) + 8 * (j >> 2) + 4 * lg2;
            SCw[dl * 32 + l31] = o0[j];
            SCw[(32 + dl) * 32 + l31] = o1[j];
        }
        if (lg2 == 0) {
            SCw[2048 + l31] = m;
            SCw[2048 + 32 + l31] = l;
        }
    }
    __syncthreads();
    if (w == 0) {
        float* SC1 = (float*)(smem + 0);
        float* SC2 = (float*)(smem + 8448);
        float* SC3 = (float*)(smem + 16896);
        __hip_bfloat16* OL = (__hip_bfloat16*)(smem + 25344);
        float m1 = SC1[2048 + l31], l1 = SC1[2048 + 32 + l31];
        float m2 = SC2[2048 + l31], l2 = SC2[2048 + 32 + l31];
        float m3 = SC3[2048 + l31], l3 = SC3[2048 + 32 + l31];
        float M = fmaxf(fmaxf(m, m1), fmaxf(m2, m3));
        float e0 = __builtin_amdgcn_exp2f((m - M) * KS2);
        float e1 = __builtin_amdgcn_exp2f((m1 - M) * KS2);
        float e2 = __builtin_amdgcn_exp2f((m2 - M) * KS2);
        float e3 = __builtin_amdgcn_exp2f((m3 - M) * KS2);
        float L = l * e0 + l1 * e1 + l2 * e2 + l3 * e3;
        float linv = 1.0f / L;
#pragma unroll
        for (int od = 0; od < 2; od++) {
#pragma unroll
            for (int g = 0; g < 4; g++) {
                int dbase = od * 32 + 8 * g + 4 * lg2;
                ushort4 w4;
#pragma unroll
                for (int r = 0; r < 4; r++) {
                    int d = dbase + r;
                    float self = od ? o1[4 * g + r] : o0[4 * g + r];
                    float v = self * e0 + SC1[d * 32 + l31] * e1 +
                              SC2[d * 32 + l31] * e2 + SC3[d * 32 + l31] * e3;
                    v *= linv;
                    ((unsigned short*)&w4)[r] = f2bf_bits(v);
                }
                *reinterpret_cast<ushort4*>(&OL[l31 * 72 + dbase]) = w4;
            }
        }
    }
    __syncthreads();
    // coalesced store: 256 threads cover 32 q x 64 d
    {
        __hip_bfloat16* OL = (__hip_bfloat16*)(smem + 25344);
        int r = tid >> 3, c = (tid & 7) * 8;
        __hip_bfloat16* dst = AO + (size_t)(bbase + q0 + r) * DMODEL + h * HDIM + c;
        *reinterpret_cast<uint4*>(dst) = *reinterpret_cast<const uint4*>(&OL[r * 72 + c]);
    }
}

// ---------------- launch ----------------

extern "C" void kernel_launch(void* const* d_in, const int* in_sizes, int n_in,
                              void* d_out, int out_size, void* d_ws, size_t ws_size,
                              hipStream_t stream) {
    const float* hidden = (const float*)d_in[0];   // [2,2048,768]
    const float* w_attn = (const float*)d_in[1];   // [768,2304]
    const float* b_attn = (const float*)d_in[2];   // [2304]
    const float* w_proj = (const float*)d_in[3];   // [768,768]
    const float* b_proj = (const float*)d_in[4];   // [768]
    float* out = (float*)d_out;                    // [2,2048,768]

    char* ws = (char*)d_ws;
    __hip_bfloat16* Xb  = (__hip_bfloat16*)(ws + 0);         // 4096*768*2 = 6291456
    __hip_bfloat16* Wta = (__hip_bfloat16*)(ws + 6291456);   // 2304*768*2
    __hip_bfloat16* Wtp = (__hip_bfloat16*)(ws + 9830400);   // 768*768*2
    __hip_bfloat16* Qpb = (__hip_bfloat16*)(ws + 11010048);  // 24*131072*2 = 6291456
    __hip_bfloat16* Kpb = (__hip_bfloat16*)(ws + 17301504);  // 6291456
    __hip_bfloat16* Vpb = (__hip_bfloat16*)(ws + 23592960);  // 6291456
    __hip_bfloat16* AO  = (__hip_bfloat16*)(ws + 29884416);  // 4096*768*2

    const int M = BATCH * SEQ;  // 4096

    prep_fused<<<dim3(5376), dim3(256), 0, stream>>>(hidden, Xb, w_attn, Wta, w_proj, Wtp);
    gemm_qkv<<<dim3(576), dim3(256), 0, stream>>>(Xb, Wta, b_attn, Qpb, Kpb, Vpb, M, QKVD, DMODEL);
    flash_attn<<<dim3(1536), dim3(256), 0, stream>>>(Qpb, Kpb, Vpb, AO);
    gemm_proj64<<<dim3(768), dim3(256), 0, stream>>>(AO, Wtp, b_proj, out, M, DMODEL, DMODEL);
}